// Round 3
// baseline (291.299 us; speedup 1.0000x reference)
//
#include <hip/hip_runtime.h>
#include <stdint.h>
#include <type_traits>

typedef unsigned short u16;
typedef __attribute__((ext_vector_type(8))) short bf16x8;
typedef __attribute__((ext_vector_type(4))) float f32x4;

#define TSEQ   2048
#define DMODEL 1024
#define NHEAD  16
#define DHEAD  64
#define SCALE2 0.18033688011112042f   // (1/sqrt(64)) * log2(e)

__device__ __forceinline__ u16 f2bf(float f) {
  union { float f; uint32_t u; } v; v.f = f;
  uint32_t r = v.u + 0x7FFFu + ((v.u >> 16) & 1u);  // RNE
  return (u16)(r >> 16);
}

// async global->LDS, 16B per lane. dst must be wave-uniform; src is per-lane.
__device__ __forceinline__ void gload16(const u16* src, u16* dst) {
  __builtin_amdgcn_global_load_lds(
      (const __attribute__((address_space(1))) void*)src,
      (__attribute__((address_space(3))) void*)dst, 16, 0, 0);
}

// ---------------- fused f32 -> bf16 conversion (all 6 inputs, 1 launch) --------------
__global__ void cvt_all(const float* __restrict__ x_q, const float* __restrict__ x_kv,
                        const float* __restrict__ w_q, const float* __restrict__ w_k,
                        const float* __restrict__ w_v, const float* __restrict__ w_o,
                        u16* __restrict__ dst) {
  int i = blockIdx.x * blockDim.x + threadIdx.x;  // float4 index, < 3M
  const float4* src;
  if (i < (1 << 20)) {
    src = (const float4*)x_q + i;
  } else if (i < (2 << 20)) {
    src = (const float4*)x_kv + (i - (1 << 20));
  } else {
    int r = i - (2 << 20);
    int k = r >> 18;
    int off = r & ((1 << 18) - 1);
    const float* w = (k == 0) ? w_q : (k == 1) ? w_k : (k == 2) ? w_v : w_o;
    src = (const float4*)w + off;
  }
  float4 f = *src;
  ushort4 o;
  o.x = f2bf(f.x); o.y = f2bf(f.y); o.z = f2bf(f.z); o.w = f2bf(f.w);
  ((ushort4*)dst)[i] = o;
}

// ---------------- GEMM: C[M,N] = A[M,K] @ W[N,K]^T (m97-style gload_lds staging) -----
template <typename OUT_T, bool TRANSZ2>
__global__ __launch_bounds__(256, 2)
void gemm_bt(const u16* A0, const u16* W0, void* C0,
             const u16* A1, const u16* W1, void* C1,
             const u16* A2, const u16* W2, void* C2,
             int M, int N, int K) {
  const u16* A = A0; const u16* W = W0; void* Cv = C0;
  if (blockIdx.z == 1) { A = A1; W = W1; Cv = C1; }
  if (blockIdx.z == 2) { A = A2; W = W2; Cv = C2; }

  __shared__ u16 lA[128 * 64];
  __shared__ u16 lB[128 * 64];

  const int tid  = threadIdx.x;
  const int lane = tid & 63;
  const int wid  = tid >> 6;
  const int wr = wid >> 1, wc = wid & 1;
  const int g = lane >> 4, l15 = lane & 15;
  const int row0 = blockIdx.y * 128;
  const int col0 = blockIdx.x * 128;
  const int lrow = lane >> 3;        // 0..7
  const int lcol = (lane & 7) * 8;   // 0..56 (16B chunks)

  const f32x4 vz = {0.f, 0.f, 0.f, 0.f};
  f32x4 acc[4][4];
#pragma unroll
  for (int m = 0; m < 4; ++m)
#pragma unroll
    for (int n = 0; n < 4; ++n) acc[m][n] = vz;

  for (int k0 = 0; k0 < K; k0 += 64) {
    __syncthreads();
#pragma unroll
    for (int i = 0; i < 4; ++i) {
      int r = wid * 32 + i * 8;
      gload16(&A[(size_t)(row0 + r + lrow) * K + k0 + lcol], &lA[r * 64]);
      gload16(&W[(size_t)(col0 + r + lrow) * K + k0 + lcol], &lB[r * 64]);
    }
    __syncthreads();
#pragma unroll
    for (int kk = 0; kk < 2; ++kk) {
      bf16x8 af[4], bfr[4];
#pragma unroll
      for (int m = 0; m < 4; ++m)
        af[m] = *(const bf16x8*)&lA[(wr * 64 + m * 16 + l15) * 64 + kk * 32 + g * 8];
#pragma unroll
      for (int n = 0; n < 4; ++n)
        bfr[n] = *(const bf16x8*)&lB[(wc * 64 + n * 16 + l15) * 64 + kk * 32 + g * 8];
#pragma unroll
      for (int m = 0; m < 4; ++m)
#pragma unroll
        for (int n = 0; n < 4; ++n)
          acc[m][n] = __builtin_amdgcn_mfma_f32_16x16x32_bf16(af[m], bfr[n], acc[m][n], 0, 0, 0);
    }
  }

  if (TRANSZ2 && blockIdx.z == 2) {
    u16* C = (u16*)Cv;
#pragma unroll
    for (int m = 0; m < 4; ++m)
#pragma unroll
      for (int n = 0; n < 4; ++n) {
        const int c = col0 + wc * 64 + n * 16 + l15;     // channel = h*64+d
        const size_t rowbase = ((size_t)((c >> 6)) * DHEAD + (c & 63)) * TSEQ;
#pragma unroll
        for (int j = 0; j < 4; ++j) {
          const int r = row0 + wr * 64 + m * 16 + g * 4 + j;  // token
          const int b = r >> 11, t = r & 2047;
          C[(size_t)b * NHEAD * DHEAD * TSEQ + rowbase + t] = f2bf(acc[m][n][j]);
        }
      }
  } else {
    OUT_T* C = (OUT_T*)Cv;
#pragma unroll
    for (int m = 0; m < 4; ++m)
#pragma unroll
      for (int n = 0; n < 4; ++n) {
        const int r = row0 + wr * 64 + m * 16 + g * 4;
        const int c = col0 + wc * 64 + n * 16 + l15;
#pragma unroll
        for (int j = 0; j < 4; ++j) {
          if constexpr (std::is_same_v<OUT_T, u16>)
            C[(size_t)(r + j) * N + c] = f2bf(acc[m][n][j]);
          else
            C[(size_t)(r + j) * N + c] = acc[m][n][j];
        }
      }
  }
}

// ---------------- fused attention, S^T orientation, no K/V LDS staging ----------------
// K and V^T per (b,h) are 256 KB each -> L2-resident (XCD swizzle groups all 16
// q-blocks of a bh on one XCD). Phase 1 is barrier-free. Phase 2 only stages P in LDS.
__global__ __launch_bounds__(256, 2)
void attn_fused(const u16* __restrict__ Qb, const u16* __restrict__ Kb,
                const u16* __restrict__ VTb, float* __restrict__ attn,
                u16* __restrict__ Ob) {
  __shared__ u16 lP[128 * 136];    // P tile [q:128][t:128+pad]
  __shared__ float lL[2][128];
  __shared__ float lInv[128];

  const int tid  = threadIdx.x;
  const int lane = tid & 63;
  const int wid  = tid >> 6;
  const int wq = wid & 1, wt = wid >> 1;
  const int g = lane >> 4, l15 = lane & 15;

  // XCD-aware remap: all 16 q-blocks of a bh land on the same XCD.
  // flat dispatch id -> xcd = flat & 7 (round-robin), idx = flat >> 3.
  const int flat = blockIdx.x + 16 * blockIdx.y;
  const int xcd  = flat & 7;
  const int idx  = flat >> 3;          // 0..63
  const int bh   = xcd + 8 * (idx >> 4);
  const int q0   = (idx & 15) * 128;
  const int b    = bh >> 4;

  const size_t xbase  = (size_t)b * TSEQ * DMODEL + (size_t)(bh & 15) * DHEAD;
  const size_t vtbase = (size_t)bh * DHEAD * TSEQ;

  // Q fragments in registers (b-operand: rows q = wq*64+n*16+l15)
  bf16x8 qf[4][2];
#pragma unroll
  for (int n = 0; n < 4; ++n)
#pragma unroll
    for (int kk = 0; kk < 2; ++kk)
      qf[n][kk] = *(const bf16x8*)&Qb[xbase + (size_t)(q0 + wq * 64 + n * 16 + l15) * DMODEL + kk * 32 + g * 8];

  const f32x4 vz = {0.f, 0.f, 0.f, 0.f};
  float psum[4] = {0.f, 0.f, 0.f, 0.f};

  // per-lane K base: row t = wt*64 + m*16 + l15, bytes kk*64 + g*16
  const u16* kbase = Kb + xbase + (size_t)(wt * 64 + l15) * DMODEL + g * 8;

  // ---------------- phase 1: exp-sums (no barriers) ----------------
  for (int t0 = 0; t0 < TSEQ; t0 += 128) {
    f32x4 s[4][4];
#pragma unroll
    for (int m = 0; m < 4; ++m)
#pragma unroll
      for (int n = 0; n < 4; ++n) s[m][n] = vz;
#pragma unroll
    for (int kk = 0; kk < 2; ++kk) {
      bf16x8 kf[4];
#pragma unroll
      for (int m = 0; m < 4; ++m)
        kf[m] = *(const bf16x8*)&kbase[(size_t)(t0 + m * 16) * DMODEL + kk * 32];
#pragma unroll
      for (int m = 0; m < 4; ++m)
#pragma unroll
        for (int n = 0; n < 4; ++n)
          s[m][n] = __builtin_amdgcn_mfma_f32_16x16x32_bf16(kf[m], qf[n][kk], s[m][n], 0, 0, 0);
    }
#pragma unroll
    for (int m = 0; m < 4; ++m)
#pragma unroll
      for (int n = 0; n < 4; ++n)
#pragma unroll
        for (int j = 0; j < 4; ++j)
          psum[n] += __builtin_amdgcn_exp2f(s[m][n][j] * SCALE2);
  }

  // reduce over g (lanes sharing q differ only in bits 4..5)
#pragma unroll
  for (int n = 0; n < 4; ++n) {
    psum[n] += __shfl_xor(psum[n], 16);
    psum[n] += __shfl_xor(psum[n], 32);
  }
  if (lane < 16) {
#pragma unroll
    for (int n = 0; n < 4; ++n) lL[wt][wq * 64 + n * 16 + lane] = psum[n];
  }
  __syncthreads();
  if (tid < 128) lInv[tid] = 1.0f / (lL[0][tid] + lL[1][tid]);
  __syncthreads();
  float inv_n[4];
#pragma unroll
  for (int n = 0; n < 4; ++n) inv_n[n] = lInv[wq * 64 + n * 16 + l15];

  // ---------------- phase 2: recompute, write attn (nt), PV ----------------
  f32x4 accO[2][4];
#pragma unroll
  for (int mi = 0; mi < 2; ++mi)
#pragma unroll
    for (int ni = 0; ni < 4; ++ni) accO[mi][ni] = vz;

  // per-lane V^T base: row d = ni*16 + l15, bytes t0*2 + kt*64 + g*16
  const u16* vbase = VTb + vtbase + (size_t)l15 * TSEQ + g * 8;

  for (int t0 = 0; t0 < TSEQ; t0 += 128) {
    f32x4 s[4][4];
#pragma unroll
    for (int m = 0; m < 4; ++m)
#pragma unroll
      for (int n = 0; n < 4; ++n) s[m][n] = vz;
#pragma unroll
    for (int kk = 0; kk < 2; ++kk) {
      bf16x8 kf[4];
#pragma unroll
      for (int m = 0; m < 4; ++m)
        kf[m] = *(const bf16x8*)&kbase[(size_t)(t0 + m * 16) * DMODEL + kk * 32];
#pragma unroll
      for (int m = 0; m < 4; ++m)
#pragma unroll
        for (int n = 0; n < 4; ++n)
          s[m][n] = __builtin_amdgcn_mfma_f32_16x16x32_bf16(kf[m], qf[n][kk], s[m][n], 0, 0, 0);
    }

    // early-issue all V^T fragment loads; they complete under the exp/store VALU
    bf16x8 vf[4][4];
#pragma unroll
    for (int kt = 0; kt < 4; ++kt)
#pragma unroll
      for (int ni = 0; ni < 4; ++ni)
        vf[kt][ni] = *(const bf16x8*)&vbase[(size_t)(ni * 16) * TSEQ + t0 + kt * 32];

#pragma unroll
    for (int m = 0; m < 4; ++m)
#pragma unroll
      for (int n = 0; n < 4; ++n) {
        const int q  = wq * 64 + n * 16 + l15;
        const int tt = wt * 64 + m * 16 + g * 4;
        f32x4 pv;
        u16 pb[4];
#pragma unroll
        for (int j = 0; j < 4; ++j) {
          float p = __builtin_amdgcn_exp2f(s[m][n][j] * SCALE2);
          pv[j] = p * inv_n[n];
          pb[j] = f2bf(p);
        }
        __builtin_nontemporal_store(pv, (f32x4*)&attn[((size_t)bh * TSEQ + q0 + q) * TSEQ + t0 + tt]);
        uint64_t pk = (uint64_t)pb[0] | ((uint64_t)pb[1] << 16) |
                      ((uint64_t)pb[2] << 32) | ((uint64_t)pb[3] << 48);
        *(uint64_t*)&lP[q * 136 + tt] = pk;
      }
    __syncthreads();

    // PV: wave owns 32 q rows x 64 d cols, k over the 128-t tile
#pragma unroll
    for (int kt = 0; kt < 4; ++kt) {
      bf16x8 pf[2];
#pragma unroll
      for (int mi = 0; mi < 2; ++mi)
        pf[mi] = *(const bf16x8*)&lP[(wid * 32 + mi * 16 + l15) * 136 + kt * 32 + g * 8];
#pragma unroll
      for (int mi = 0; mi < 2; ++mi)
#pragma unroll
        for (int ni = 0; ni < 4; ++ni)
          accO[mi][ni] = __builtin_amdgcn_mfma_f32_16x16x32_bf16(pf[mi], vf[kt][ni], accO[mi][ni], 0, 0, 0);
    }
    __syncthreads();
  }

  // epilogue: normalize, write O bf16 in [B,T,C]
#pragma unroll
  for (int mi = 0; mi < 2; ++mi)
#pragma unroll
    for (int ni = 0; ni < 4; ++ni)
#pragma unroll
      for (int j = 0; j < 4; ++j) {
        int q = wid * 32 + mi * 16 + g * 4 + j;
        Ob[xbase + (size_t)(q0 + q) * DMODEL + ni * 16 + l15] = f2bf(accO[mi][ni][j] * lInv[q]);
      }
}

// ---------------- launch ----------------
extern "C" void kernel_launch(void* const* d_in, const int* in_sizes, int n_in,
                              void* d_out, int out_size, void* d_ws, size_t ws_size,
                              hipStream_t stream) {
  const float* x_q  = (const float*)d_in[0];
  const float* x_kv = (const float*)d_in[1];
  const float* w_q  = (const float*)d_in[2];
  const float* w_k  = (const float*)d_in[3];
  const float* w_v  = (const float*)d_in[4];
  const float* w_o  = (const float*)d_in[5];

  float* out  = (float*)d_out;
  float* attn = out + (size_t)2 * TSEQ * DMODEL;

  const size_t X_E = (size_t)2 * TSEQ * DMODEL;  // 4M
  const size_t W_E = (size_t)DMODEL * DMODEL;    // 1M

  u16* ws     = (u16*)d_ws;
  u16* xq_bf  = ws;                 // 4M
  u16* xkv_bf = xq_bf + X_E;        // 4M
  u16* wq_bf  = xkv_bf + X_E;       // 1M
  u16* wk_bf  = wq_bf + W_E;
  u16* wv_bf  = wk_bf + W_E;
  u16* wo_bf  = wv_bf + W_E;
  u16* q_bf   = wo_bf + W_E;        // 4M
  u16* k_bf   = q_bf + X_E;         // 4M
  u16* vt_bf  = k_bf + X_E;         // 4M  (transposed [BH][D][T])
  u16* o_bf   = vt_bf + X_E;        // 4M

  // all f32->bf16 conversions, one launch (3M float4)
  cvt_all<<<dim3(3 * 1024 * 1024 / 256), dim3(256), 0, stream>>>(
      x_q, x_kv, w_q, w_k, w_v, w_o, ws);

  // fused QKV projections (z=2 writes V transposed)
  {
    dim3 grid(DMODEL / 128, (2 * TSEQ) / 128, 3);
    gemm_bt<u16, true><<<grid, dim3(256), 0, stream>>>(
        xq_bf,  wq_bf, q_bf,
        xkv_bf, wk_bf, k_bf,
        xkv_bf, wv_bf, vt_bf,
        2 * TSEQ, DMODEL, DMODEL);
  }

  // attention
  attn_fused<<<dim3(TSEQ / 128, 2 * NHEAD), dim3(256), 0, stream>>>(
      q_bf, k_bf, vt_bf, attn, o_bf);

  // output projection -> f32
  {
    dim3 grid(DMODEL / 128, (2 * TSEQ) / 128, 1);
    gemm_bt<float, false><<<grid, dim3(256), 0, stream>>>(
        o_bf, wo_bf, out,
        o_bf, wo_bf, out,
        o_bf, wo_bf, out,
        2 * TSEQ, DMODEL, DMODEL);
  }
}

// Round 4
// 283.137 us; speedup vs baseline: 1.0288x; 1.0288x over previous
//
#include <hip/hip_runtime.h>
#include <stdint.h>
#include <type_traits>

typedef unsigned short u16;
typedef __attribute__((ext_vector_type(8))) short bf16x8;
typedef __attribute__((ext_vector_type(4))) float f32x4;

#define TSEQ   2048
#define DMODEL 1024
#define NHEAD  16
#define DHEAD  64
#define SCALE2 0.18033688011112042f   // (1/sqrt(64)) * log2(e)

__device__ __forceinline__ u16 f2bf(float f) {
  union { float f; uint32_t u; } v; v.f = f;
  uint32_t r = v.u + 0x7FFFu + ((v.u >> 16) & 1u);  // RNE
  return (u16)(r >> 16);
}

__device__ __forceinline__ float bf2f(uint32_t bits) {
  union { uint32_t u; float f; } v; v.u = bits << 16;
  return v.f;
}

// async global->LDS, 16B per lane. dst must be wave-uniform; src is per-lane.
__device__ __forceinline__ void gload16(const u16* src, u16* dst) {
  __builtin_amdgcn_global_load_lds(
      (const __attribute__((address_space(1))) void*)src,
      (__attribute__((address_space(3))) void*)dst, 16, 0, 0);
}

// ---------------- fused f32 -> bf16 conversion (all 6 inputs, 1 launch) --------------
__global__ void cvt_all(const float* __restrict__ x_q, const float* __restrict__ x_kv,
                        const float* __restrict__ w_q, const float* __restrict__ w_k,
                        const float* __restrict__ w_v, const float* __restrict__ w_o,
                        u16* __restrict__ dst) {
  int i = blockIdx.x * blockDim.x + threadIdx.x;  // float4 index, < 3M
  const float4* src;
  if (i < (1 << 20)) {
    src = (const float4*)x_q + i;
  } else if (i < (2 << 20)) {
    src = (const float4*)x_kv + (i - (1 << 20));
  } else {
    int r = i - (2 << 20);
    int k = r >> 18;
    int off = r & ((1 << 18) - 1);
    const float* w = (k == 0) ? w_q : (k == 1) ? w_k : (k == 2) ? w_v : w_o;
    src = (const float4*)w + off;
  }
  float4 f = *src;
  ushort4 o;
  o.x = f2bf(f.x); o.y = f2bf(f.y); o.z = f2bf(f.z); o.w = f2bf(f.w);
  ((ushort4*)dst)[i] = o;
}

// ---------------- GEMM: C[M,N] = A[M,K] @ W[N,K]^T ----------------
// Tile BM x 128, BK=64, 4 waves. BM in {64,128}. 3 blocks/CU via launch_bounds.
template <typename OUT_T, bool TRANSZ2, int BM>
__global__ __launch_bounds__(256, 3)
void gemm_bt(const u16* A0, const u16* W0, void* C0,
             const u16* A1, const u16* W1, void* C1,
             const u16* A2, const u16* W2, void* C2,
             int M, int N, int K) {
  const u16* A = A0; const u16* W = W0; void* Cv = C0;
  if (blockIdx.z == 1) { A = A1; W = W1; Cv = C1; }
  if (blockIdx.z == 2) { A = A2; W = W2; Cv = C2; }

  constexpr int MW = BM / 32;        // m-fragments per wave
  __shared__ u16 lA[BM * 64];
  __shared__ u16 lB[128 * 64];

  const int tid  = threadIdx.x;
  const int lane = tid & 63;
  const int wid  = tid >> 6;
  const int wr = wid >> 1, wc = wid & 1;
  const int g = lane >> 4, l15 = lane & 15;
  const int row0 = blockIdx.y * BM;
  const int col0 = blockIdx.x * 128;
  const int lrow = lane >> 3;        // 0..7
  const int lcol = (lane & 7) * 8;   // 0..56 (16B chunks)

  const f32x4 vz = {0.f, 0.f, 0.f, 0.f};
  f32x4 acc[MW][4];
#pragma unroll
  for (int m = 0; m < MW; ++m)
#pragma unroll
    for (int n = 0; n < 4; ++n) acc[m][n] = vz;

  for (int k0 = 0; k0 < K; k0 += 64) {
    __syncthreads();
#pragma unroll
    for (int i = 0; i < BM / 32; ++i) {
      int r = wid * (BM / 4) + i * 8;
      gload16(&A[(size_t)(row0 + r + lrow) * K + k0 + lcol], &lA[r * 64]);
    }
#pragma unroll
    for (int i = 0; i < 4; ++i) {
      int r = wid * 32 + i * 8;
      gload16(&W[(size_t)(col0 + r + lrow) * K + k0 + lcol], &lB[r * 64]);
    }
    __syncthreads();
#pragma unroll
    for (int kk = 0; kk < 2; ++kk) {
      bf16x8 af[MW], bfr[4];
#pragma unroll
      for (int m = 0; m < MW; ++m)
        af[m] = *(const bf16x8*)&lA[(wr * (BM / 2) + m * 16 + l15) * 64 + kk * 32 + g * 8];
#pragma unroll
      for (int n = 0; n < 4; ++n)
        bfr[n] = *(const bf16x8*)&lB[(wc * 64 + n * 16 + l15) * 64 + kk * 32 + g * 8];
#pragma unroll
      for (int m = 0; m < MW; ++m)
#pragma unroll
        for (int n = 0; n < 4; ++n)
          acc[m][n] = __builtin_amdgcn_mfma_f32_16x16x32_bf16(af[m], bfr[n], acc[m][n], 0, 0, 0);
    }
  }

  if constexpr (TRANSZ2) {
    if (blockIdx.z == 2) {
      // transposed write: vT[(b*NHEAD+h)*DHEAD + d][t], packed 4 tokens -> u64
      u16* C = (u16*)Cv;
#pragma unroll
      for (int m = 0; m < MW; ++m)
#pragma unroll
        for (int n = 0; n < 4; ++n) {
          const int c = col0 + wc * 64 + n * 16 + l15;     // channel = h*64+d
          const size_t rowbase = ((size_t)(c >> 6) * DHEAD + (c & 63)) * TSEQ;
          const int r = row0 + wr * (BM / 2) + m * 16 + g * 4;  // token (4 contiguous)
          const int b = r >> 11, t = r & 2047;
          uint64_t pk = (uint64_t)f2bf(acc[m][n][0]) |
                        ((uint64_t)f2bf(acc[m][n][1]) << 16) |
                        ((uint64_t)f2bf(acc[m][n][2]) << 32) |
                        ((uint64_t)f2bf(acc[m][n][3]) << 48);
          *(uint64_t*)&C[(size_t)b * NHEAD * DHEAD * TSEQ + rowbase + t] = pk;
        }
      return;
    }
  }
  {
    OUT_T* C = (OUT_T*)Cv;
#pragma unroll
    for (int m = 0; m < MW; ++m)
#pragma unroll
      for (int n = 0; n < 4; ++n) {
        const int r = row0 + wr * (BM / 2) + m * 16 + g * 4;
        const int c = col0 + wc * 64 + n * 16 + l15;
#pragma unroll
        for (int j = 0; j < 4; ++j) {
          if constexpr (std::is_same_v<OUT_T, u16>)
            C[(size_t)(r + j) * N + c] = f2bf(acc[m][n][j]);
          else
            C[(size_t)(r + j) * N + c] = acc[m][n][j];
        }
      }
  }
}

// ---------------- fused attention, S^T orientation, no K/V LDS staging ----------------
// Phase 1 barrier-free exp-sums. Phase 2: dbuf lP, ONE barrier per tile; attn stores
// issued post-barrier from register-held bf16 P (drain overlaps PV + next tile's QK).
__global__ __launch_bounds__(256, 2)
void attn_fused(const u16* __restrict__ Qb, const u16* __restrict__ Kb,
                const u16* __restrict__ VTb, float* __restrict__ attn,
                u16* __restrict__ Ob) {
  __shared__ u16 lP[2][128 * 136];   // P tile dbuf [q:128][t:128+pad]
  __shared__ float lL[2][128];
  __shared__ float lInv[128];

  const int tid  = threadIdx.x;
  const int lane = tid & 63;
  const int wid  = tid >> 6;
  const int wq = wid & 1, wt = wid >> 1;
  const int g = lane >> 4, l15 = lane & 15;

  // XCD-aware remap: all 16 q-blocks of a bh land on the same XCD.
  const int flat = blockIdx.x + 16 * blockIdx.y;
  const int xcd  = flat & 7;
  const int idx  = flat >> 3;          // 0..63
  const int bh   = xcd + 8 * (idx >> 4);
  const int q0   = (idx & 15) * 128;
  const int b    = bh >> 4;

  const size_t xbase  = (size_t)b * TSEQ * DMODEL + (size_t)(bh & 15) * DHEAD;
  const size_t vtbase = (size_t)bh * DHEAD * TSEQ;

  // Q fragments in registers (b-operand: rows q = wq*64+n*16+l15)
  bf16x8 qf[4][2];
#pragma unroll
  for (int n = 0; n < 4; ++n)
#pragma unroll
    for (int kk = 0; kk < 2; ++kk)
      qf[n][kk] = *(const bf16x8*)&Qb[xbase + (size_t)(q0 + wq * 64 + n * 16 + l15) * DMODEL + kk * 32 + g * 8];

  const f32x4 vz = {0.f, 0.f, 0.f, 0.f};
  float psum[4] = {0.f, 0.f, 0.f, 0.f};

  // per-lane K base: row t = wt*64 + m*16 + l15, halves kk
  const u16* kbase = Kb + xbase + (size_t)(wt * 64 + l15) * DMODEL + g * 8;

  // ---------------- phase 1: exp-sums (no barriers) ----------------
  for (int t0 = 0; t0 < TSEQ; t0 += 128) {
    f32x4 s[4][4];
#pragma unroll
    for (int m = 0; m < 4; ++m)
#pragma unroll
      for (int n = 0; n < 4; ++n) s[m][n] = vz;
#pragma unroll
    for (int kk = 0; kk < 2; ++kk) {
      bf16x8 kf[4];
#pragma unroll
      for (int m = 0; m < 4; ++m)
        kf[m] = *(const bf16x8*)&kbase[(size_t)(t0 + m * 16) * DMODEL + kk * 32];
#pragma unroll
      for (int m = 0; m < 4; ++m)
#pragma unroll
        for (int n = 0; n < 4; ++n)
          s[m][n] = __builtin_amdgcn_mfma_f32_16x16x32_bf16(kf[m], qf[n][kk], s[m][n], 0, 0, 0);
    }
#pragma unroll
    for (int m = 0; m < 4; ++m)
#pragma unroll
      for (int n = 0; n < 4; ++n)
#pragma unroll
        for (int j = 0; j < 4; ++j)
          psum[n] += __builtin_amdgcn_exp2f(s[m][n][j] * SCALE2);
  }

  // reduce over g (lanes sharing q differ only in bits 4..5)
#pragma unroll
  for (int n = 0; n < 4; ++n) {
    psum[n] += __shfl_xor(psum[n], 16);
    psum[n] += __shfl_xor(psum[n], 32);
  }
  if (lane < 16) {
#pragma unroll
    for (int n = 0; n < 4; ++n) lL[wt][wq * 64 + n * 16 + lane] = psum[n];
  }
  __syncthreads();
  if (tid < 128) lInv[tid] = 1.0f / (lL[0][tid] + lL[1][tid]);
  __syncthreads();
  float inv_n[4];
#pragma unroll
  for (int n = 0; n < 4; ++n) inv_n[n] = lInv[wq * 64 + n * 16 + l15];

  // ---------------- phase 2: recompute, PV, post-barrier attn stores ----------------
  f32x4 accO[2][4];
#pragma unroll
  for (int mi = 0; mi < 2; ++mi)
#pragma unroll
    for (int ni = 0; ni < 4; ++ni) accO[mi][ni] = vz;

  // per-lane V^T base: row d = ni*16 + l15
  const u16* vbase = VTb + vtbase + (size_t)l15 * TSEQ + g * 8;

  int cur = 0;
  for (int t0 = 0; t0 < TSEQ; t0 += 128) {
    u16* lPc = lP[cur];

    f32x4 s[4][4];
#pragma unroll
    for (int m = 0; m < 4; ++m)
#pragma unroll
      for (int n = 0; n < 4; ++n) s[m][n] = vz;
#pragma unroll
    for (int kk = 0; kk < 2; ++kk) {
      bf16x8 kf[4];
#pragma unroll
      for (int m = 0; m < 4; ++m)
        kf[m] = *(const bf16x8*)&kbase[(size_t)(t0 + m * 16) * DMODEL + kk * 32];
#pragma unroll
      for (int m = 0; m < 4; ++m)
#pragma unroll
        for (int n = 0; n < 4; ++n)
          s[m][n] = __builtin_amdgcn_mfma_f32_16x16x32_bf16(kf[m], qf[n][kk], s[m][n], 0, 0, 0);
    }

    // early-issue all V^T fragment loads; complete under exp/pack
    bf16x8 vf[4][4];
#pragma unroll
    for (int kt = 0; kt < 4; ++kt)
#pragma unroll
      for (int ni = 0; ni < 4; ++ni)
        vf[kt][ni] = *(const bf16x8*)&vbase[(size_t)(ni * 16) * TSEQ + t0 + kt * 32];

    // exp -> bf16 pack; keep in regs AND write to LDS for PV
    uint64_t pk[4][4];
#pragma unroll
    for (int m = 0; m < 4; ++m)
#pragma unroll
      for (int n = 0; n < 4; ++n) {
        const int q  = wq * 64 + n * 16 + l15;
        const int tt = wt * 64 + m * 16 + g * 4;
        u16 pb[4];
#pragma unroll
        for (int j = 0; j < 4; ++j)
          pb[j] = f2bf(__builtin_amdgcn_exp2f(s[m][n][j] * SCALE2));
        uint64_t pkk = (uint64_t)pb[0] | ((uint64_t)pb[1] << 16) |
                       ((uint64_t)pb[2] << 32) | ((uint64_t)pb[3] << 48);
        pk[m][n] = pkk;
        *(uint64_t*)&lPc[q * 136 + tt] = pkk;
      }
    __syncthreads();

    // attn stores (post-barrier: drain overlaps PV + next tile; exact bf16->f32)
#pragma unroll
    for (int m = 0; m < 4; ++m)
#pragma unroll
      for (int n = 0; n < 4; ++n) {
        const int q  = wq * 64 + n * 16 + l15;
        const int tt = wt * 64 + m * 16 + g * 4;
        f32x4 pv;
#pragma unroll
        for (int j = 0; j < 4; ++j)
          pv[j] = bf2f((uint32_t)(pk[m][n] >> (16 * j)) & 0xFFFFu) * inv_n[n];
        __builtin_nontemporal_store(pv, (f32x4*)&attn[((size_t)bh * TSEQ + q0 + q) * TSEQ + t0 + tt]);
      }

    // PV: wave owns 32 q rows x 64 d cols, k over the 128-t tile
#pragma unroll
    for (int kt = 0; kt < 4; ++kt) {
      bf16x8 pf[2];
#pragma unroll
      for (int mi = 0; mi < 2; ++mi)
        pf[mi] = *(const bf16x8*)&lPc[(wid * 32 + mi * 16 + l15) * 136 + kt * 32 + g * 8];
#pragma unroll
      for (int mi = 0; mi < 2; ++mi)
#pragma unroll
        for (int ni = 0; ni < 4; ++ni)
          accO[mi][ni] = __builtin_amdgcn_mfma_f32_16x16x32_bf16(pf[mi], vf[kt][ni], accO[mi][ni], 0, 0, 0);
    }
    cur ^= 1;
  }

  // epilogue: normalize, write O bf16 in [B,T,C]
#pragma unroll
  for (int mi = 0; mi < 2; ++mi)
#pragma unroll
    for (int ni = 0; ni < 4; ++ni)
#pragma unroll
      for (int j = 0; j < 4; ++j) {
        int q = wid * 32 + mi * 16 + g * 4 + j;
        Ob[xbase + (size_t)(q0 + q) * DMODEL + ni * 16 + l15] = f2bf(accO[mi][ni][j] * lInv[q]);
      }
}

// ---------------- launch ----------------
extern "C" void kernel_launch(void* const* d_in, const int* in_sizes, int n_in,
                              void* d_out, int out_size, void* d_ws, size_t ws_size,
                              hipStream_t stream) {
  const float* x_q  = (const float*)d_in[0];
  const float* x_kv = (const float*)d_in[1];
  const float* w_q  = (const float*)d_in[2];
  const float* w_k  = (const float*)d_in[3];
  const float* w_v  = (const float*)d_in[4];
  const float* w_o  = (const float*)d_in[5];

  float* out  = (float*)d_out;
  float* attn = out + (size_t)2 * TSEQ * DMODEL;

  const size_t X_E = (size_t)2 * TSEQ * DMODEL;  // 4M
  const size_t W_E = (size_t)DMODEL * DMODEL;    // 1M

  u16* ws     = (u16*)d_ws;
  u16* xq_bf  = ws;                 // 4M
  u16* xkv_bf = xq_bf + X_E;        // 4M
  u16* wq_bf  = xkv_bf + X_E;       // 1M
  u16* wk_bf  = wq_bf + W_E;
  u16* wv_bf  = wk_bf + W_E;
  u16* wo_bf  = wv_bf + W_E;
  u16* q_bf   = wo_bf + W_E;        // 4M
  u16* k_bf   = q_bf + X_E;         // 4M
  u16* vt_bf  = k_bf + X_E;         // 4M  (transposed [BH][D][T])
  u16* o_bf   = vt_bf + X_E;        // 4M

  // all f32->bf16 conversions, one launch (3M float4)
  cvt_all<<<dim3(3 * 1024 * 1024 / 256), dim3(256), 0, stream>>>(
      x_q, x_kv, w_q, w_k, w_v, w_o, ws);

  // fused QKV projections (z=2 writes V transposed), 768 blocks = 3/CU
  {
    dim3 grid(DMODEL / 128, (2 * TSEQ) / 128, 3);
    gemm_bt<u16, true, 128><<<grid, dim3(256), 0, stream>>>(
        xq_bf,  wq_bf, q_bf,
        xkv_bf, wk_bf, k_bf,
        xkv_bf, wv_bf, vt_bf,
        2 * TSEQ, DMODEL, DMODEL);
  }

  // attention
  attn_fused<<<dim3(TSEQ / 128, 2 * NHEAD), dim3(256), 0, stream>>>(
      q_bf, k_bf, vt_bf, attn, o_bf);

  // output projection -> f32: 64x128 tiles, 512 blocks = 2/CU
  {
    dim3 grid(DMODEL / 128, (2 * TSEQ) / 64, 1);
    gemm_bt<float, false, 64><<<grid, dim3(256), 0, stream>>>(
        o_bf, wo_bf, out,
        o_bf, wo_bf, out,
        o_bf, wo_bf, out,
        2 * TSEQ, DMODEL, DMODEL);
  }
}

// Round 5
// 228.261 us; speedup vs baseline: 1.2762x; 1.2404x over previous
//
#include <hip/hip_runtime.h>
#include <stdint.h>
#include <type_traits>

typedef unsigned short u16;
typedef __attribute__((ext_vector_type(8))) short bf16x8;
typedef __attribute__((ext_vector_type(4))) float f32x4;

#define TSEQ   2048
#define DMODEL 1024
#define NHEAD  16
#define DHEAD  64
#define SCALE2 0.18033688011112042f   // (1/sqrt(64)) * log2(e)

__device__ __forceinline__ u16 f2bf(float f) {
  union { float f; uint32_t u; } v; v.f = f;
  uint32_t r = v.u + 0x7FFFu + ((v.u >> 16) & 1u);  // RNE
  return (u16)(r >> 16);
}

__device__ __forceinline__ float bf2f(uint32_t bits) {
  union { uint32_t u; float f; } v; v.u = bits << 16;
  return v.f;
}

// async global->LDS, 16B per lane. dst must be wave-uniform; src is per-lane.
__device__ __forceinline__ void gload16(const u16* src, u16* dst) {
  __builtin_amdgcn_global_load_lds(
      (const __attribute__((address_space(1))) void*)src,
      (__attribute__((address_space(3))) void*)dst, 16, 0, 0);
}

// ---------------- fused f32 -> bf16 conversion (all 6 inputs, 1 launch) --------------
__global__ void cvt_all(const float* __restrict__ x_q, const float* __restrict__ x_kv,
                        const float* __restrict__ w_q, const float* __restrict__ w_k,
                        const float* __restrict__ w_v, const float* __restrict__ w_o,
                        u16* __restrict__ dst) {
  int i = blockIdx.x * blockDim.x + threadIdx.x;  // float4 index, < 3M
  const float4* src;
  if (i < (1 << 20)) {
    src = (const float4*)x_q + i;
  } else if (i < (2 << 20)) {
    src = (const float4*)x_kv + (i - (1 << 20));
  } else {
    int r = i - (2 << 20);
    int k = r >> 18;
    int off = r & ((1 << 18) - 1);
    const float* w = (k == 0) ? w_q : (k == 1) ? w_k : (k == 2) ? w_v : w_o;
    src = (const float4*)w + off;
  }
  float4 f = *src;
  ushort4 o;
  o.x = f2bf(f.x); o.y = f2bf(f.y); o.z = f2bf(f.z); o.w = f2bf(f.w);
  ((ushort4*)dst)[i] = o;
}

// ---------------- GEMM: C[M,N] = A[M,K] @ W[N,K]^T ----------------
template <typename OUT_T, bool TRANSZ2, int BM>
__global__ __launch_bounds__(256, 3)
void gemm_bt(const u16* A0, const u16* W0, void* C0,
             const u16* A1, const u16* W1, void* C1,
             const u16* A2, const u16* W2, void* C2,
             int M, int N, int K) {
  const u16* A = A0; const u16* W = W0; void* Cv = C0;
  if (blockIdx.z == 1) { A = A1; W = W1; Cv = C1; }
  if (blockIdx.z == 2) { A = A2; W = W2; Cv = C2; }

  constexpr int MW = BM / 32;        // m-fragments per wave
  __shared__ u16 lA[BM * 64];
  __shared__ u16 lB[128 * 64];

  const int tid  = threadIdx.x;
  const int lane = tid & 63;
  const int wid  = tid >> 6;
  const int wr = wid >> 1, wc = wid & 1;
  const int g = lane >> 4, l15 = lane & 15;
  const int row0 = blockIdx.y * BM;
  const int col0 = blockIdx.x * 128;
  const int lrow = lane >> 3;        // 0..7
  const int lcol = (lane & 7) * 8;   // 0..56 (16B chunks)

  const f32x4 vz = {0.f, 0.f, 0.f, 0.f};
  f32x4 acc[MW][4];
#pragma unroll
  for (int m = 0; m < MW; ++m)
#pragma unroll
    for (int n = 0; n < 4; ++n) acc[m][n] = vz;

  for (int k0 = 0; k0 < K; k0 += 64) {
    __syncthreads();
#pragma unroll
    for (int i = 0; i < BM / 32; ++i) {
      int r = wid * (BM / 4) + i * 8;
      gload16(&A[(size_t)(row0 + r + lrow) * K + k0 + lcol], &lA[r * 64]);
    }
#pragma unroll
    for (int i = 0; i < 4; ++i) {
      int r = wid * 32 + i * 8;
      gload16(&W[(size_t)(col0 + r + lrow) * K + k0 + lcol], &lB[r * 64]);
    }
    __syncthreads();
#pragma unroll
    for (int kk = 0; kk < 2; ++kk) {
      bf16x8 af[MW], bfr[4];
#pragma unroll
      for (int m = 0; m < MW; ++m)
        af[m] = *(const bf16x8*)&lA[(wr * (BM / 2) + m * 16 + l15) * 64 + kk * 32 + g * 8];
#pragma unroll
      for (int n = 0; n < 4; ++n)
        bfr[n] = *(const bf16x8*)&lB[(wc * 64 + n * 16 + l15) * 64 + kk * 32 + g * 8];
#pragma unroll
      for (int m = 0; m < MW; ++m)
#pragma unroll
        for (int n = 0; n < 4; ++n)
          acc[m][n] = __builtin_amdgcn_mfma_f32_16x16x32_bf16(af[m], bfr[n], acc[m][n], 0, 0, 0);
    }
  }

  if constexpr (TRANSZ2) {
    if (blockIdx.z == 2) {
      // transposed write: vT[(b*NHEAD+h)*DHEAD + d][t], packed 4 tokens -> u64
      u16* C = (u16*)Cv;
#pragma unroll
      for (int m = 0; m < MW; ++m)
#pragma unroll
        for (int n = 0; n < 4; ++n) {
          const int c = col0 + wc * 64 + n * 16 + l15;     // channel = h*64+d
          const size_t rowbase = ((size_t)(c >> 6) * DHEAD + (c & 63)) * TSEQ;
          const int r = row0 + wr * (BM / 2) + m * 16 + g * 4;  // token (4 contiguous)
          const int b = r >> 11, t = r & 2047;
          uint64_t pk = (uint64_t)f2bf(acc[m][n][0]) |
                        ((uint64_t)f2bf(acc[m][n][1]) << 16) |
                        ((uint64_t)f2bf(acc[m][n][2]) << 32) |
                        ((uint64_t)f2bf(acc[m][n][3]) << 48);
          *(uint64_t*)&C[(size_t)b * NHEAD * DHEAD * TSEQ + rowbase + t] = pk;
        }
      return;
    }
  }
  {
    OUT_T* C = (OUT_T*)Cv;
#pragma unroll
    for (int m = 0; m < MW; ++m)
#pragma unroll
      for (int n = 0; n < 4; ++n) {
        const int r = row0 + wr * (BM / 2) + m * 16 + g * 4;
        const int c = col0 + wc * 64 + n * 16 + l15;
#pragma unroll
        for (int j = 0; j < 4; ++j) {
          if constexpr (std::is_same_v<OUT_T, u16>)
            C[(size_t)(r + j) * N + c] = f2bf(acc[m][n][j]);
          else
            C[(size_t)(r + j) * N + c] = acc[m][n][j];
        }
      }
  }
}

// ---------------- fused attention ----------------
// Phase 1: barrier-free exp-sums. Phase 2: QK -> P(bf16)->LDS -> barrier ->
// coalesced attn stores read back from LDS (1KB contiguous per instr) -> PV.
// Register lifetimes kept disjoint (s dies before vf issues; no pk carry) to
// avoid scratch spills.
__global__ __launch_bounds__(256, 2)
void attn_fused(const u16* __restrict__ Qb, const u16* __restrict__ Kb,
                const u16* __restrict__ VTb, float* __restrict__ attn,
                u16* __restrict__ Ob) {
  __shared__ u16 lP[2][128 * 136];   // P tile dbuf [q:128][t:128+pad]
  __shared__ float lL[2][128];
  __shared__ float lInv[128];

  const int tid  = threadIdx.x;
  const int lane = tid & 63;
  const int wid  = tid >> 6;
  const int wq = wid & 1, wt = wid >> 1;
  const int g = lane >> 4, l15 = lane & 15;

  // XCD-aware remap: all 16 q-blocks of a bh land on the same XCD.
  const int flat = blockIdx.x + 16 * blockIdx.y;
  const int xcd  = flat & 7;
  const int idx  = flat >> 3;          // 0..63
  const int bh   = xcd + 8 * (idx >> 4);
  const int q0   = (idx & 15) * 128;
  const int b    = bh >> 4;

  const size_t xbase  = (size_t)b * TSEQ * DMODEL + (size_t)(bh & 15) * DHEAD;
  const size_t vtbase = (size_t)bh * DHEAD * TSEQ;

  // Q fragments in registers (b-operand: rows q = wq*64+n*16+l15)
  bf16x8 qf[4][2];
#pragma unroll
  for (int n = 0; n < 4; ++n)
#pragma unroll
    for (int kk = 0; kk < 2; ++kk)
      qf[n][kk] = *(const bf16x8*)&Qb[xbase + (size_t)(q0 + wq * 64 + n * 16 + l15) * DMODEL + kk * 32 + g * 8];

  const f32x4 vz = {0.f, 0.f, 0.f, 0.f};
  float psum[4] = {0.f, 0.f, 0.f, 0.f};

  // per-lane K base: row t = wt*64 + m*16 + l15, halves kk
  const u16* kbase = Kb + xbase + (size_t)(wt * 64 + l15) * DMODEL + g * 8;

  // ---------------- phase 1: exp-sums (no barriers) ----------------
  for (int t0 = 0; t0 < TSEQ; t0 += 128) {
    f32x4 s[4][4];
#pragma unroll
    for (int m = 0; m < 4; ++m)
#pragma unroll
      for (int n = 0; n < 4; ++n) s[m][n] = vz;
#pragma unroll
    for (int kk = 0; kk < 2; ++kk) {
      bf16x8 kf[4];
#pragma unroll
      for (int m = 0; m < 4; ++m)
        kf[m] = *(const bf16x8*)&kbase[(size_t)(t0 + m * 16) * DMODEL + kk * 32];
#pragma unroll
      for (int m = 0; m < 4; ++m)
#pragma unroll
        for (int n = 0; n < 4; ++n)
          s[m][n] = __builtin_amdgcn_mfma_f32_16x16x32_bf16(kf[m], qf[n][kk], s[m][n], 0, 0, 0);
    }
#pragma unroll
    for (int m = 0; m < 4; ++m)
#pragma unroll
      for (int n = 0; n < 4; ++n)
#pragma unroll
        for (int j = 0; j < 4; ++j)
          psum[n] += __builtin_amdgcn_exp2f(s[m][n][j] * SCALE2);
  }

  // reduce over g (lanes sharing q differ only in bits 4..5)
#pragma unroll
  for (int n = 0; n < 4; ++n) {
    psum[n] += __shfl_xor(psum[n], 16);
    psum[n] += __shfl_xor(psum[n], 32);
  }
  if (lane < 16) {
#pragma unroll
    for (int n = 0; n < 4; ++n) lL[wt][wq * 64 + n * 16 + lane] = psum[n];
  }
  __syncthreads();
  if (tid < 128) lInv[tid] = 1.0f / (lL[0][tid] + lL[1][tid]);
  __syncthreads();

  // normalization factors for the coalesced store loop: c-th chunk row = c*8 + (tid>>5)
  float inv_c[16];
#pragma unroll
  for (int c = 0; c < 16; ++c) inv_c[c] = lInv[c * 8 + (tid >> 5)];

  // ---------------- phase 2 ----------------
  f32x4 accO[2][4];
#pragma unroll
  for (int mi = 0; mi < 2; ++mi)
#pragma unroll
    for (int ni = 0; ni < 4; ++ni) accO[mi][ni] = vz;

  // per-lane V^T base: row d = ni*16 + l15
  const u16* vbase = VTb + vtbase + (size_t)l15 * TSEQ + g * 8;
  // coalesced attn store base for this thread
  float* attn_tb = attn + ((size_t)bh * TSEQ + q0) * TSEQ;

  int cur = 0;
  for (int t0 = 0; t0 < TSEQ; t0 += 128) {
    u16* lPc = lP[cur];

    // ---- QK^T (S^T orientation) ----
    {
      f32x4 s[4][4];
#pragma unroll
      for (int m = 0; m < 4; ++m)
#pragma unroll
        for (int n = 0; n < 4; ++n) s[m][n] = vz;
#pragma unroll
      for (int kk = 0; kk < 2; ++kk) {
        bf16x8 kf[4];
#pragma unroll
        for (int m = 0; m < 4; ++m)
          kf[m] = *(const bf16x8*)&kbase[(size_t)(t0 + m * 16) * DMODEL + kk * 32];
#pragma unroll
        for (int m = 0; m < 4; ++m)
#pragma unroll
          for (int n = 0; n < 4; ++n)
            s[m][n] = __builtin_amdgcn_mfma_f32_16x16x32_bf16(kf[m], qf[n][kk], s[m][n], 0, 0, 0);
      }

      // exp -> bf16 pack -> LDS (s dies here, before the barrier)
#pragma unroll
      for (int m = 0; m < 4; ++m)
#pragma unroll
        for (int n = 0; n < 4; ++n) {
          const int q  = wq * 64 + n * 16 + l15;
          const int tt = wt * 64 + m * 16 + g * 4;
          u16 pb[4];
#pragma unroll
          for (int j = 0; j < 4; ++j)
            pb[j] = f2bf(__builtin_amdgcn_exp2f(s[m][n][j] * SCALE2));
          uint64_t pkk = (uint64_t)pb[0] | ((uint64_t)pb[1] << 16) |
                         ((uint64_t)pb[2] << 32) | ((uint64_t)pb[3] << 48);
          *(uint64_t*)&lPc[q * 136 + tt] = pkk;
        }
    }
    __syncthreads();

    // ---- V^T fragment loads (issue first; complete under the store loop) ----
    bf16x8 vf[4][4];
#pragma unroll
    for (int kt = 0; kt < 4; ++kt)
#pragma unroll
      for (int ni = 0; ni < 4; ++ni)
        vf[kt][ni] = *(const bf16x8*)&vbase[(size_t)(ni * 16) * TSEQ + t0 + kt * 32];

    // ---- coalesced attn stores: each instr covers 1KB contiguous ----
#pragma unroll
    for (int c = 0; c < 16; ++c) {
      const int fl = c * 1024 + tid * 4;
      const int q  = fl >> 7;
      const int t  = fl & 127;
      uint64_t pkv = *(const uint64_t*)&lPc[q * 136 + t];
      const float inv = inv_c[c];
      f32x4 pv;
#pragma unroll
      for (int j = 0; j < 4; ++j)
        pv[j] = bf2f((uint32_t)(pkv >> (16 * j)) & 0xFFFFu) * inv;
      __builtin_nontemporal_store(pv, (f32x4*)&attn_tb[(size_t)q * TSEQ + t0 + t]);
    }

    // ---- PV: wave owns 32 q rows x 64 d cols, k over the 128-t tile ----
#pragma unroll
    for (int kt = 0; kt < 4; ++kt) {
      bf16x8 pf[2];
#pragma unroll
      for (int mi = 0; mi < 2; ++mi)
        pf[mi] = *(const bf16x8*)&lPc[(wid * 32 + mi * 16 + l15) * 136 + kt * 32 + g * 8];
#pragma unroll
      for (int mi = 0; mi < 2; ++mi)
#pragma unroll
        for (int ni = 0; ni < 4; ++ni)
          accO[mi][ni] = __builtin_amdgcn_mfma_f32_16x16x32_bf16(pf[mi], vf[kt][ni], accO[mi][ni], 0, 0, 0);
    }
    cur ^= 1;
  }

  // epilogue: normalize, write O bf16 in [B,T,C]
#pragma unroll
  for (int mi = 0; mi < 2; ++mi)
#pragma unroll
    for (int ni = 0; ni < 4; ++ni)
#pragma unroll
      for (int j = 0; j < 4; ++j) {
        int q = wid * 32 + mi * 16 + g * 4 + j;
        Ob[xbase + (size_t)(q0 + q) * DMODEL + ni * 16 + l15] = f2bf(accO[mi][ni][j] * lInv[q]);
      }
}

// ---------------- launch ----------------
extern "C" void kernel_launch(void* const* d_in, const int* in_sizes, int n_in,
                              void* d_out, int out_size, void* d_ws, size_t ws_size,
                              hipStream_t stream) {
  const float* x_q  = (const float*)d_in[0];
  const float* x_kv = (const float*)d_in[1];
  const float* w_q  = (const float*)d_in[2];
  const float* w_k  = (const float*)d_in[3];
  const float* w_v  = (const float*)d_in[4];
  const float* w_o  = (const float*)d_in[5];

  float* out  = (float*)d_out;
  float* attn = out + (size_t)2 * TSEQ * DMODEL;

  const size_t X_E = (size_t)2 * TSEQ * DMODEL;  // 4M
  const size_t W_E = (size_t)DMODEL * DMODEL;    // 1M

  u16* ws     = (u16*)d_ws;
  u16* xq_bf  = ws;                 // 4M
  u16* xkv_bf = xq_bf + X_E;        // 4M
  u16* wq_bf  = xkv_bf + X_E;       // 1M
  u16* wk_bf  = wq_bf + W_E;
  u16* wv_bf  = wk_bf + W_E;
  u16* wo_bf  = wv_bf + W_E;
  u16* q_bf   = wo_bf + W_E;        // 4M
  u16* k_bf   = q_bf + X_E;         // 4M
  u16* vt_bf  = k_bf + X_E;         // 4M  (transposed [BH][D][T])
  u16* o_bf   = vt_bf + X_E;        // 4M

  // all f32->bf16 conversions, one launch (3M float4)
  cvt_all<<<dim3(3 * 1024 * 1024 / 256), dim3(256), 0, stream>>>(
      x_q, x_kv, w_q, w_k, w_v, w_o, ws);

  // fused QKV projections (z=2 writes V transposed), 768 blocks = 3/CU
  {
    dim3 grid(DMODEL / 128, (2 * TSEQ) / 128, 3);
    gemm_bt<u16, true, 128><<<grid, dim3(256), 0, stream>>>(
        xq_bf,  wq_bf, q_bf,
        xkv_bf, wk_bf, k_bf,
        xkv_bf, wv_bf, vt_bf,
        2 * TSEQ, DMODEL, DMODEL);
  }

  // attention
  attn_fused<<<dim3(TSEQ / 128, 2 * NHEAD), dim3(256), 0, stream>>>(
      q_bf, k_bf, vt_bf, attn, o_bf);

  // output projection -> f32: 64x128 tiles, 512 blocks = 2/CU
  {
    dim3 grid(DMODEL / 128, (2 * TSEQ) / 64, 1);
    gemm_bt<float, false, 64><<<grid, dim3(256), 0, stream>>>(
        o_bf, wo_bf, out,
        o_bf, wo_bf, out,
        o_bf, wo_bf, out,
        2 * TSEQ, DMODEL, DMODEL);
  }
}